// Round 2
// baseline (1020.548 us; speedup 1.0000x reference)
//
#include <hip/hip_runtime.h>
#include <cstddef>

// dims
#define B_ 16
#define A_ 859
#define N_ 5
#define D_ 32
#define H1_ 128
#define DV_ 16
#define NV_ 8
#define DOUT_ 32
#define ACT_ 8
#define ROWS_ (A_ * N_)          // 4295 rows per batch in the nbr GEMM

// ---------------- K1: x = relu(relu(agent@W1+b1)@W2+b2) ----------------
__global__ __launch_bounds__(128) void mlp_kernel(
    const float* __restrict__ agent, const float* __restrict__ w1,
    const float* __restrict__ b1, const float* __restrict__ w2,
    const float* __restrict__ b2, float* __restrict__ xout) {
  __shared__ float w1L[32 * 128], w2L[128 * 32], b1L[128], b2L[32];
  __shared__ float xrowL[32], hidL[128];
  const int t = threadIdx.x;
  for (int i = t; i < 32 * 128; i += 128) w1L[i] = w1[i];
  for (int i = t; i < 128 * 32; i += 128) w2L[i] = w2[i];
  b1L[t] = b1[t];
  if (t < 32) b2L[t] = b2[t];
  __syncthreads();
  for (int g = 0; g < 16; ++g) {
    size_t aidx = (size_t)blockIdx.x * 16 + g;
    if (t < 32) xrowL[t] = agent[aidx * 32 + t];
    __syncthreads();
    float h = b1L[t];
#pragma unroll
    for (int k = 0; k < 32; ++k) h = fmaf(xrowL[k], w1L[k * 128 + t], h);
    hidL[t] = fmaxf(h, 0.f);
    __syncthreads();
    if (t < 32) {
      float o = b2L[t];
#pragma unroll
      for (int k = 0; k < 128; ++k) o = fmaf(hidL[k], w2L[k * 32 + t], o);
      xout[aidx * 32 + t] = fmaxf(o, 0.f);
    }
    __syncthreads();
  }
}

// ---------------- K2: nbr[b, r=i*5+n, d] = sum_a adj[b,r,a] * x[b,a,d] ----
// 64-row x 32-col tile per block (1088 blocks -> 4.25/CU), K chunks of 32.
// XOR-swizzled adj LDS: quad kq stored at kq ^ ((row>>1)&7); read-side
// float4 ds_reads are conflict-free across the 8 broadcast groups of a wave.
__global__ __launch_bounds__(256) void gemm_nbr_kernel(
    const float* __restrict__ adj, const float* __restrict__ x,
    float* __restrict__ nbr) {
  __shared__ __align__(16) float adjL[64 * 36];
  __shared__ __align__(16) float xL[32 * 36];
  const int b = blockIdx.y;
  const int rowBase = blockIdx.x * 64;
  const int t = threadIdx.x;
  const int cg = t & 7, rg = t >> 3;        // rg in [0,32)
  const int c0 = cg << 2, r0 = rg << 1;     // 2 rows, 4 cols per thread
  const int swz = rg & 7;                   // == ((r0+i)>>1)&7 for i in {0,1}
  const float* adjB = adj + (size_t)b * ROWS_ * A_;
  const float* xB = x + (size_t)b * A_ * D_;
  float acc[2][4] = {};
  for (int kt = 0; kt < 27; ++kt) {
    const int kBase = kt * 32;
    __syncthreads();
#pragma unroll
    for (int j = 0; j < 8; ++j) {
      int flat = t + j * 256;
      int row = flat >> 5, k = flat & 31;
      int grow = rowBase + row, gk = kBase + k;
      float v = (grow < ROWS_ && gk < A_) ? adjB[(size_t)grow * A_ + gk] : 0.f;
      adjL[row * 36 + (((k >> 2) ^ ((row >> 1) & 7)) << 2) + (k & 3)] = v;
    }
#pragma unroll
    for (int j = 0; j < 4; ++j) {
      int flat = t + j * 256;
      int kk = flat >> 5, d = flat & 31;
      int gk = kBase + kk;
      xL[kk * 36 + d] = (gk < A_) ? xB[(size_t)gk * 32 + d] : 0.f;
    }
    __syncthreads();
#pragma unroll
    for (int kq = 0; kq < 8; ++kq) {
      float4 xa[4];
#pragma unroll
      for (int kk = 0; kk < 4; ++kk)
        xa[kk] = *(const float4*)&xL[(kq * 4 + kk) * 36 + c0];
#pragma unroll
      for (int i = 0; i < 2; ++i) {
        float4 a4 = *(const float4*)&adjL[(r0 + i) * 36 + ((kq ^ swz) << 2)];
        const float ak0 = a4.x, ak1 = a4.y, ak2 = a4.z, ak3 = a4.w;
        acc[i][0] = fmaf(ak0, xa[0].x, acc[i][0]);
        acc[i][1] = fmaf(ak0, xa[0].y, acc[i][1]);
        acc[i][2] = fmaf(ak0, xa[0].z, acc[i][2]);
        acc[i][3] = fmaf(ak0, xa[0].w, acc[i][3]);
        acc[i][0] = fmaf(ak1, xa[1].x, acc[i][0]);
        acc[i][1] = fmaf(ak1, xa[1].y, acc[i][1]);
        acc[i][2] = fmaf(ak1, xa[1].z, acc[i][2]);
        acc[i][3] = fmaf(ak1, xa[1].w, acc[i][3]);
        acc[i][0] = fmaf(ak2, xa[2].x, acc[i][0]);
        acc[i][1] = fmaf(ak2, xa[2].y, acc[i][1]);
        acc[i][2] = fmaf(ak2, xa[2].z, acc[i][2]);
        acc[i][3] = fmaf(ak2, xa[2].w, acc[i][3]);
        acc[i][0] = fmaf(ak3, xa[3].x, acc[i][0]);
        acc[i][1] = fmaf(ak3, xa[3].y, acc[i][1]);
        acc[i][2] = fmaf(ak3, xa[3].z, acc[i][2]);
        acc[i][3] = fmaf(ak3, xa[3].w, acc[i][3]);
      }
    }
  }
#pragma unroll
  for (int i = 0; i < 2; ++i) {
    int grow = rowBase + r0 + i;
    if (grow < ROWS_) {
      float4 v = make_float4(acc[i][0], acc[i][1], acc[i][2], acc[i][3]);
      *(float4*)&nbr[((size_t)b * ROWS_ + grow) * 32 + c0] = v;
    }
  }
}

// ---------------- K3: ah/nr projections + scores ----------------
// scores[b,a,h,e] = sum_d relu(x@ahw+b)[d*8+h] * relu(nbr@nrw+b)[e][d*8+h]
__global__ __launch_bounds__(128) void heads_scores_kernel(
    const float* __restrict__ x, const float* __restrict__ nbr,
    const float* __restrict__ ahw, const float* __restrict__ ahb,
    const float* __restrict__ nrw, const float* __restrict__ nrb,
    float* __restrict__ scores) {
  __shared__ float ahwL[4096], nrwL[4096], ahbL[128], nrbL[128];
  __shared__ float xrowL[32], nbrL[160], ahL[128], nrL[5 * 128];
  const int t = threadIdx.x;
  for (int i = t; i < 4096; i += 128) { ahwL[i] = ahw[i]; nrwL[i] = nrw[i]; }
  ahbL[t] = ahb[t];
  nrbL[t] = nrb[t];
  __syncthreads();
  for (int g = 0; g < 16; ++g) {
    size_t aidx = (size_t)blockIdx.x * 16 + g;
    if (t < 32) xrowL[t] = x[aidx * 32 + t];
    for (int i = t; i < 160; i += 128) nbrL[i] = nbr[aidx * 160 + i];
    __syncthreads();
    float ah = ahbL[t];
    float nr0 = nrbL[t], nr1 = nr0, nr2 = nr0, nr3 = nr0, nr4 = nr0;
#pragma unroll
    for (int k = 0; k < 32; ++k) {
      float wa = ahwL[k * 128 + t];
      float wn = nrwL[k * 128 + t];
      ah = fmaf(xrowL[k], wa, ah);
      nr0 = fmaf(nbrL[k], wn, nr0);
      nr1 = fmaf(nbrL[32 + k], wn, nr1);
      nr2 = fmaf(nbrL[64 + k], wn, nr2);
      nr3 = fmaf(nbrL[96 + k], wn, nr3);
      nr4 = fmaf(nbrL[128 + k], wn, nr4);
    }
    ahL[t] = fmaxf(ah, 0.f);
    nrL[t] = fmaxf(nr0, 0.f);
    nrL[128 + t] = fmaxf(nr1, 0.f);
    nrL[256 + t] = fmaxf(nr2, 0.f);
    nrL[384 + t] = fmaxf(nr3, 0.f);
    nrL[512 + t] = fmaxf(nr4, 0.f);
    __syncthreads();
    if (t < 40) {
      int h = t / 5, e = t % 5;
      float s = 0.f;
#pragma unroll
      for (int d = 0; d < 16; ++d)
        s = fmaf(ahL[d * 8 + h], nrL[e * 128 + d * 8 + h], s);
      scores[aidx * 40 + t] = s;
    }
    __syncthreads();
  }
}

// ---------------- K4: softmax stats over the AGENT axis ----------------
// per (b,h,e): max_a scores, sum_a exp(scores - max)
__global__ __launch_bounds__(256) void softmax_reduce_kernel(
    const float* __restrict__ scores, float* __restrict__ smax,
    float* __restrict__ ssum) {
  const int bi = blockIdx.x;  // b*40 + he
  const int b = bi / 40, he = bi % 40;
  const float* sp = scores + (size_t)b * A_ * 40 + he;
  __shared__ float red[4];
  const int t = threadIdx.x;
  float m = -1e30f;
  for (int a = t; a < A_; a += 256) m = fmaxf(m, sp[(size_t)a * 40]);
#pragma unroll
  for (int off = 32; off; off >>= 1) m = fmaxf(m, __shfl_xor(m, off, 64));
  if ((t & 63) == 0) red[t >> 6] = m;
  __syncthreads();
  m = fmaxf(fmaxf(red[0], red[1]), fmaxf(red[2], red[3]));
  __syncthreads();
  float s = 0.f;
  for (int a = t; a < A_; a += 256) s += expf(sp[(size_t)a * 40] - m);
#pragma unroll
  for (int off = 32; off; off >>= 1) s += __shfl_xor(s, off, 64);
  if ((t & 63) == 0) red[t >> 6] = s;
  __syncthreads();
  if (t == 0) {
    smax[bi] = m;
    ssum[bi] = red[0] + red[1] + red[2] + red[3];
  }
}

// ---------------- K5: att + nh + head-mean + output proj ----------------
__global__ __launch_bounds__(128) void att_out_kernel(
    const float* __restrict__ nbr, const float* __restrict__ scores,
    const float* __restrict__ smax, const float* __restrict__ ssum,
    const float* __restrict__ nhw, const float* __restrict__ nhb,
    const float* __restrict__ ow, const float* __restrict__ ob,
    float* __restrict__ attBase,  // d_out + 128 + l*A_*40
    float* __restrict__ xout) {
  __shared__ float nhwL[4096], nhbL[128], owL[512], obL[32];
  __shared__ float nbrL[160], nhL[5 * 128], attL[40], outdL[16];
  const int t = threadIdx.x;
  for (int i = t; i < 4096; i += 128) nhwL[i] = nhw[i];
  nhbL[t] = nhb[t];
  for (int i = t; i < 512; i += 128) owL[i] = ow[i];
  if (t < 32) obL[t] = ob[t];
  __syncthreads();
  for (int g = 0; g < 16; ++g) {
    size_t aidx = (size_t)blockIdx.x * 16 + g;
    for (int i = t; i < 160; i += 128) nbrL[i] = nbr[aidx * 160 + i];
    __syncthreads();
    float n0 = nhbL[t], n1 = n0, n2 = n0, n3 = n0, n4 = n0;
#pragma unroll
    for (int k = 0; k < 32; ++k) {
      float w = nhwL[k * 128 + t];
      n0 = fmaf(nbrL[k], w, n0);
      n1 = fmaf(nbrL[32 + k], w, n1);
      n2 = fmaf(nbrL[64 + k], w, n2);
      n3 = fmaf(nbrL[96 + k], w, n3);
      n4 = fmaf(nbrL[128 + k], w, n4);
    }
    nhL[t] = fmaxf(n0, 0.f);
    nhL[128 + t] = fmaxf(n1, 0.f);
    nhL[256 + t] = fmaxf(n2, 0.f);
    nhL[384 + t] = fmaxf(n3, 0.f);
    nhL[512 + t] = fmaxf(n4, 0.f);
    if (t < 40) {
      size_t b = aidx / A_;
      size_t i = aidx % A_;
      float a = expf(scores[aidx * 40 + t] - smax[b * 40 + t]) / ssum[b * 40 + t];
      attL[t] = a;
      attBase[((size_t)b * (2 * A_) + i) * 40 + t] = a;  // att_record slot
    }
    __syncthreads();
    if (t < 16) {
      float od = 0.f;
#pragma unroll
      for (int e = 0; e < 5; ++e)
#pragma unroll
        for (int h = 0; h < 8; ++h)
          od = fmaf(attL[h * 5 + e], nhL[e * 128 + t * 8 + h], od);
      outdL[t] = od * 0.125f;
    }
    __syncthreads();
    if (t < 32) {
      float o = obL[t];
#pragma unroll
      for (int d = 0; d < 16; ++d) o = fmaf(outdL[d], owL[d * 32 + t], o);
      xout[aidx * 32 + t] = fmaxf(o, 0.f);
    }
    __syncthreads();
  }
}

// ---------------- K6: q = (x @ fin_w + fin_b)[:, 0, :] ----------------
__global__ __launch_bounds__(128) void qout_kernel(
    const float* __restrict__ x, const float* __restrict__ fw,
    const float* __restrict__ fb, float* __restrict__ q) {
  const int t = threadIdx.x;
  const int b = t >> 3, act = t & 7;
  const float* xr = x + (size_t)b * A_ * 32;  // agent 0 row
  float s = fb[act];
#pragma unroll
  for (int d = 0; d < 32; ++d) s = fmaf(xr[d], fw[d * 8 + act], s);
  q[t] = s;
}

extern "C" void kernel_launch(void* const* d_in, const int* in_sizes, int n_in,
                              void* d_out, int out_size, void* d_ws,
                              size_t ws_size, hipStream_t stream) {
  (void)in_sizes; (void)n_in; (void)out_size; (void)ws_size;
  const float* agent = (const float*)d_in[0];
  const float* adj = (const float*)d_in[1];
  const float* mlp_w1 = (const float*)d_in[2];
  const float* mlp_b1 = (const float*)d_in[3];
  const float* mlp_w2 = (const float*)d_in[4];
  const float* mlp_b2 = (const float*)d_in[5];
  const float* fin_w = (const float*)d_in[6];
  const float* fin_b = (const float*)d_in[7];
  const float* lw[2][8];
  for (int l = 0; l < 2; ++l)
    for (int j = 0; j < 8; ++j) lw[l][j] = (const float*)d_in[8 + l * 8 + j];
  // lw[l]: 0 ah_w, 1 ah_b, 2 nr_w, 3 nr_b, 4 nh_w, 5 nh_b, 6 o_w, 7 o_b

  float* out = (float*)d_out;
  float* ws = (float*)d_ws;
  float* x0 = ws;                          // B*A*D floats
  float* x1 = x0 + (size_t)B_ * A_ * D_;
  float* nbr = x1 + (size_t)B_ * A_ * D_;  // B*ROWS*D
  float* scores = nbr + (size_t)B_ * ROWS_ * D_;  // B*A*40
  float* smax = scores + (size_t)B_ * A_ * 40;    // 640
  float* ssum = smax + 640;                       // 640

  const int agBlocks = (B_ * A_) / 16;  // 859
  mlp_kernel<<<agBlocks, 128, 0, stream>>>(agent, mlp_w1, mlp_b1, mlp_w2,
                                           mlp_b2, x0);

  float* xin = x0;
  float* xnext = x1;
  for (int l = 0; l < 2; ++l) {
    gemm_nbr_kernel<<<dim3(68, B_), 256, 0, stream>>>(adj, xin, nbr);
    heads_scores_kernel<<<agBlocks, 128, 0, stream>>>(
        xin, nbr, lw[l][0], lw[l][1], lw[l][2], lw[l][3], scores);
    softmax_reduce_kernel<<<B_ * 40, 256, 0, stream>>>(scores, smax, ssum);
    att_out_kernel<<<agBlocks, 128, 0, stream>>>(
        nbr, scores, smax, ssum, lw[l][4], lw[l][5], lw[l][6], lw[l][7],
        out + 128 + (size_t)l * A_ * 40, xnext);
    float* tmp = xin; xin = xnext; xnext = tmp;
  }
  // after the loop, xin holds the final x (in x0)
  qout_kernel<<<1, 128, 0, stream>>>(xin, fin_w, fin_b, out);
}

// Round 7
// 678.646 us; speedup vs baseline: 1.5038x; 1.5038x over previous
//
#include <hip/hip_runtime.h>
#include <cstddef>

// dims
#define B_ 16
#define A_ 859
#define N_ 5
#define D_ 32
#define H1_ 128
#define DV_ 16
#define NV_ 8
#define DOUT_ 32
#define ACT_ 8
#define ROWS_ (A_ * N_)          // 4295 rows per batch in the nbr GEMM

#define WAVE_WAIT_LDS() \
  do { asm volatile("s_waitcnt lgkmcnt(0)" ::: "memory"); \
       __builtin_amdgcn_sched_barrier(0); } while (0)

__device__ __forceinline__ void load32(const float* __restrict__ p,
                                       float* __restrict__ dst) {
#pragma unroll
  for (int j = 0; j < 8; ++j) {
    float4 v = ((const float4*)p)[j];
    dst[j * 4] = v.x; dst[j * 4 + 1] = v.y;
    dst[j * 4 + 2] = v.z; dst[j * 4 + 3] = v.w;
  }
}

// ---------------- K1: x = relu(relu(agent@W1+b1)@W2+b2) ----------------
// One agent per 64-lane wave; no inter-wave barriers in the loop.
__global__ __launch_bounds__(256) void mlp_kernel(
    const float* __restrict__ agent, const float* __restrict__ w1,
    const float* __restrict__ b1, const float* __restrict__ w2,
    const float* __restrict__ b2, float* __restrict__ xout) {
  __shared__ float w1L[4096], w2L[4096], b1L[128], b2L[32];
  __shared__ float hidS[4][128];
  const int t = threadIdx.x;
  const int w = t >> 6, L = t & 63;
  for (int i = t; i < 4096; i += 256) { w1L[i] = w1[i]; w2L[i] = w2[i]; }
  if (t < 128) b1L[t] = b1[t];
  if (t < 32) b2L[t] = b2[t];
  __syncthreads();
  for (int it = 0; it < 4; ++it) {
    size_t aidx = (size_t)blockIdx.x * 16 + w * 4 + it;
    float xs[32];
    load32(agent + aidx * 32, xs);
    float h0 = b1L[L], h1 = b1L[L + 64];
#pragma unroll
    for (int k = 0; k < 32; ++k) {
      h0 = fmaf(xs[k], w1L[k * 128 + L], h0);
      h1 = fmaf(xs[k], w1L[k * 128 + L + 64], h1);
    }
    hidS[w][L] = fmaxf(h0, 0.f);
    hidS[w][L + 64] = fmaxf(h1, 0.f);
    WAVE_WAIT_LDS();
    const int c = L & 31, kh = L >> 5;
    float o = 0.f;
#pragma unroll
    for (int kk = 0; kk < 64; ++kk) {
      int k = kh * 64 + kk;
      o = fmaf(hidS[w][k], w2L[k * 32 + c], o);
    }
    o += __shfl_xor(o, 32);
    if (L < 32) xout[aidx * 32 + c] = fmaxf(o + b2L[c], 0.f);
    WAVE_WAIT_LDS();  // WAR: reads done before next iter's writes
  }
}

// ---------------- K2: nbr[b, r=i*5+n, d] = sum_a adj[b,r,a] * x[b,a,d] ----
// 64x32 tile, register-staged DOUBLE-BUFFERED LDS (unchanged, audited).
__global__ __launch_bounds__(256) void gemm_nbr_kernel(
    const float* __restrict__ adj, const float* __restrict__ x,
    float* __restrict__ nbr) {
  __shared__ __align__(16) float adjL[2][64 * 36];
  __shared__ __align__(16) float xL[2][32 * 36];
  const int b = blockIdx.y;
  const int rowBase = blockIdx.x * 64;
  const int t = threadIdx.x;
  const int cg = t & 7, rg = t >> 3;        // rg in [0,32)
  const int c0 = cg << 2, r0 = rg << 1;     // 2 rows, 4 cols per thread
  const int swz = rg & 7;
  const float* adjB = adj + (size_t)b * ROWS_ * A_;
  const float* xB = x + (size_t)b * A_ * D_;
  const int xkk = t >> 3, xdq = t & 7;      // x tile: 1 float4 per thread

  float areg[8];
  float4 xreg;

  auto load_regs = [&](int kt) {
    const int kBase = kt * 32;
#pragma unroll
    for (int j = 0; j < 8; ++j) {
      int flat = t + j * 256;
      int row = flat >> 5, k = flat & 31;
      int grow = rowBase + row, gk = kBase + k;
      areg[j] = (grow < ROWS_ && gk < A_) ? adjB[(size_t)grow * A_ + gk] : 0.f;
    }
    int gk = kBase + xkk;
    xreg = (gk < A_) ? *(const float4*)&xB[(size_t)gk * 32 + (xdq << 2)]
                     : make_float4(0.f, 0.f, 0.f, 0.f);
  };
  auto write_lds = [&](int buf) {
#pragma unroll
    for (int j = 0; j < 8; ++j) {
      int flat = t + j * 256;
      int row = flat >> 5, k = flat & 31;
      adjL[buf][row * 36 + (((k >> 2) ^ ((row >> 1) & 7)) << 2) + (k & 3)] =
          areg[j];
    }
    *(float4*)&xL[buf][xkk * 36 + (xdq << 2)] = xreg;
  };

  load_regs(0);
  write_lds(0);
  __syncthreads();

  float acc[2][4] = {};
  for (int kt = 0; kt < 27; ++kt) {
    const int cur = kt & 1;
    if (kt + 1 < 27) load_regs(kt + 1);  // prefetch hides under compute
#pragma unroll
    for (int kq = 0; kq < 8; ++kq) {
      float4 xa[4];
#pragma unroll
      for (int kk = 0; kk < 4; ++kk)
        xa[kk] = *(const float4*)&xL[cur][(kq * 4 + kk) * 36 + c0];
#pragma unroll
      for (int i = 0; i < 2; ++i) {
        float4 a4 =
            *(const float4*)&adjL[cur][(r0 + i) * 36 + ((kq ^ swz) << 2)];
        const float ak0 = a4.x, ak1 = a4.y, ak2 = a4.z, ak3 = a4.w;
        acc[i][0] = fmaf(ak0, xa[0].x, acc[i][0]);
        acc[i][1] = fmaf(ak0, xa[0].y, acc[i][1]);
        acc[i][2] = fmaf(ak0, xa[0].z, acc[i][2]);
        acc[i][3] = fmaf(ak0, xa[0].w, acc[i][3]);
        acc[i][0] = fmaf(ak1, xa[1].x, acc[i][0]);
        acc[i][1] = fmaf(ak1, xa[1].y, acc[i][1]);
        acc[i][2] = fmaf(ak1, xa[1].z, acc[i][2]);
        acc[i][3] = fmaf(ak1, xa[1].w, acc[i][3]);
        acc[i][0] = fmaf(ak2, xa[2].x, acc[i][0]);
        acc[i][1] = fmaf(ak2, xa[2].y, acc[i][1]);
        acc[i][2] = fmaf(ak2, xa[2].z, acc[i][2]);
        acc[i][3] = fmaf(ak2, xa[2].w, acc[i][3]);
        acc[i][0] = fmaf(ak3, xa[3].x, acc[i][0]);
        acc[i][1] = fmaf(ak3, xa[3].y, acc[i][1]);
        acc[i][2] = fmaf(ak3, xa[3].z, acc[i][2]);
        acc[i][3] = fmaf(ak3, xa[3].w, acc[i][3]);
      }
    }
    if (kt + 1 < 27) {
      write_lds((kt + 1) & 1);  // other buffer: no read/write clash
      __syncthreads();          // publish tile kt+1
    }
  }
#pragma unroll
  for (int i = 0; i < 2; ++i) {
    int grow = rowBase + r0 + i;
    if (grow < ROWS_) {
      float4 v = make_float4(acc[i][0], acc[i][1], acc[i][2], acc[i][3]);
      *(float4*)&nbr[((size_t)b * ROWS_ + grow) * 32 + c0] = v;
    }
  }
}

// ---------------- K3: ah/nr projections + scores ----------------
// One agent per wave; scores layout [b][a][40] (contiguous writes).
__global__ __launch_bounds__(256) void heads_scores_kernel(
    const float* __restrict__ x, const float* __restrict__ nbr,
    const float* __restrict__ ahw, const float* __restrict__ ahb,
    const float* __restrict__ nrw, const float* __restrict__ nrb,
    float* __restrict__ scores) {
  __shared__ float ahwL[4096], nrwL[4096], ahbL[128], nrbL[128];
  __shared__ float scr[4][768];  // per wave: [0..127]=ah, [128+e*128+o]=nr
  const int t = threadIdx.x;
  const int w = t >> 6, L = t & 63;
  for (int i = t; i < 4096; i += 256) { ahwL[i] = ahw[i]; nrwL[i] = nrw[i]; }
  if (t < 128) { ahbL[t] = ahb[t]; nrbL[t] = nrb[t]; }
  __syncthreads();
  for (int it = 0; it < 4; ++it) {
    size_t aidx = (size_t)blockIdx.x * 16 + w * 4 + it;
    const float* nb = nbr + aidx * 160;
    float xs[32], ns[32], nn[32];
    load32(x + aidx * 32, xs);
    load32(nb, ns);
    float a0 = ahbL[L], a1 = ahbL[L + 64];
#pragma unroll
    for (int k = 0; k < 32; ++k) {
      a0 = fmaf(xs[k], ahwL[k * 128 + L], a0);
      a1 = fmaf(xs[k], ahwL[k * 128 + L + 64], a1);
    }
    scr[w][L] = fmaxf(a0, 0.f);
    scr[w][L + 64] = fmaxf(a1, 0.f);
    const float nb0 = nrbL[L], nb1 = nrbL[L + 64];
#pragma unroll
    for (int e = 0; e < 5; ++e) {
      if (e < 4) load32(nb + (e + 1) * 32, nn);  // prefetch next neighbor
      float c0 = nb0, c1 = nb1;
#pragma unroll
      for (int k = 0; k < 32; ++k) {
        c0 = fmaf(ns[k], nrwL[k * 128 + L], c0);
        c1 = fmaf(ns[k], nrwL[k * 128 + L + 64], c1);
      }
      scr[w][128 + e * 128 + L] = fmaxf(c0, 0.f);
      scr[w][128 + e * 128 + L + 64] = fmaxf(c1, 0.f);
#pragma unroll
      for (int j = 0; j < 32; ++j) ns[j] = nn[j];
    }
    WAVE_WAIT_LDS();
    if (L < 40) {
      int h = L / 5, e = L % 5;
      float s = 0.f;
#pragma unroll
      for (int dv = 0; dv < 16; ++dv)
        s = fmaf(scr[w][dv * 8 + h], scr[w][128 + e * 128 + dv * 8 + h], s);
      scores[aidx * 40 + L] = s;
    }
    WAVE_WAIT_LDS();  // WAR before next iteration's scratch writes
  }
}

// ---------------- K4: softmax stats over the AGENT axis ----------------
// (round-2 validated version; scores [b][a][40], strided reads via L2)
__global__ __launch_bounds__(256) void softmax_reduce_kernel(
    const float* __restrict__ scores, float* __restrict__ smax,
    float* __restrict__ ssum) {
  const int bi = blockIdx.x;  // b*40 + he
  const int b = bi / 40, he = bi % 40;
  const float* sp = scores + (size_t)b * A_ * 40 + he;
  __shared__ float red[4];
  const int t = threadIdx.x;
  float m = -1e30f;
  for (int a = t; a < A_; a += 256) m = fmaxf(m, sp[(size_t)a * 40]);
#pragma unroll
  for (int off = 32; off; off >>= 1) m = fmaxf(m, __shfl_xor(m, off, 64));
  if ((t & 63) == 0) red[t >> 6] = m;
  __syncthreads();
  m = fmaxf(fmaxf(red[0], red[1]), fmaxf(red[2], red[3]));
  __syncthreads();
  float s = 0.f;
  for (int a = t; a < A_; a += 256) s += expf(sp[(size_t)a * 40] - m);
#pragma unroll
  for (int off = 32; off; off >>= 1) s += __shfl_xor(s, off, 64);
  if ((t & 63) == 0) red[t >> 6] = s;
  __syncthreads();
  if (t == 0) {
    smax[bi] = m;
    ssum[bi] = red[0] + red[1] + red[2] + red[3];
  }
}

// ---------------- K5: att + nh + head-mean + output proj ----------------
// One agent per wave, 3 intra-wave phases.
__global__ __launch_bounds__(256) void att_out_kernel(
    const float* __restrict__ nbr, const float* __restrict__ scores,
    const float* __restrict__ smax, const float* __restrict__ ssum,
    const float* __restrict__ nhw, const float* __restrict__ nhb,
    const float* __restrict__ ow, const float* __restrict__ ob,
    float* __restrict__ attBase,  // d_out + 128 + l*A_*40
    float* __restrict__ xout) {
  __shared__ float nhwL[4096], nhbL[128], owL[512], obL[32];
  __shared__ float nhS[4][640], attS[4][40], odS[4][16];
  const int t = threadIdx.x;
  const int w = t >> 6, L = t & 63;
  for (int i = t; i < 4096; i += 256) nhwL[i] = nhw[i];
  if (t < 128) nhbL[t] = nhb[t];
  for (int i = t; i < 512; i += 256) owL[i] = ow[i];
  if (t < 32) obL[t] = ob[t];
  __syncthreads();
  for (int it = 0; it < 4; ++it) {
    size_t aidx = (size_t)blockIdx.x * 16 + w * 4 + it;
    const float* nb = nbr + aidx * 160;
    float ns[32], nn[32];
    load32(nb, ns);
    const float nb0 = nhbL[L], nb1 = nhbL[L + 64];
#pragma unroll
    for (int e = 0; e < 5; ++e) {
      if (e < 4) load32(nb + (e + 1) * 32, nn);
      float c0 = nb0, c1 = nb1;
#pragma unroll
      for (int k = 0; k < 32; ++k) {
        c0 = fmaf(ns[k], nhwL[k * 128 + L], c0);
        c1 = fmaf(ns[k], nhwL[k * 128 + L + 64], c1);
      }
      nhS[w][e * 128 + L] = fmaxf(c0, 0.f);
      nhS[w][e * 128 + L + 64] = fmaxf(c1, 0.f);
#pragma unroll
      for (int j = 0; j < 32; ++j) ns[j] = nn[j];
    }
    if (L < 40) {
      size_t b = aidx / A_, ii = aidx % A_;
      float a = expf(scores[aidx * 40 + L] - smax[b * 40 + L]) /
                ssum[b * 40 + L];
      attS[w][L] = a;
      attBase[((size_t)b * (2 * A_) + ii) * 40 + L] = a;
    }
    WAVE_WAIT_LDS();
    if (L < 16) {
      float od = 0.f;
#pragma unroll
      for (int e = 0; e < 5; ++e)
#pragma unroll
        for (int h = 0; h < 8; ++h)
          od = fmaf(attS[w][h * 5 + e], nhS[w][e * 128 + L * 8 + h], od);
      odS[w][L] = od * 0.125f;
    }
    WAVE_WAIT_LDS();
    if (L < 32) {
      float o = obL[L];
#pragma unroll
      for (int dv = 0; dv < 16; ++dv)
        o = fmaf(odS[w][dv], owL[dv * 32 + L], o);
      xout[aidx * 32 + L] = fmaxf(o, 0.f);
    }
    WAVE_WAIT_LDS();  // WAR before next iteration's scratch writes
  }
}

// ---------------- K6: q = (x @ fin_w + fin_b)[:, 0, :] ----------------
__global__ __launch_bounds__(128) void qout_kernel(
    const float* __restrict__ x, const float* __restrict__ fw,
    const float* __restrict__ fb, float* __restrict__ q) {
  const int t = threadIdx.x;
  const int b = t >> 3, act = t & 7;
  const float* xr = x + (size_t)b * A_ * 32;  // agent 0 row
  float s = fb[act];
#pragma unroll
  for (int d = 0; d < 32; ++d) s = fmaf(xr[d], fw[d * 8 + act], s);
  q[t] = s;
}

extern "C" void kernel_launch(void* const* d_in, const int* in_sizes, int n_in,
                              void* d_out, int out_size, void* d_ws,
                              size_t ws_size, hipStream_t stream) {
  (void)in_sizes; (void)n_in; (void)out_size; (void)ws_size;
  const float* agent = (const float*)d_in[0];
  const float* adj = (const float*)d_in[1];
  const float* mlp_w1 = (const float*)d_in[2];
  const float* mlp_b1 = (const float*)d_in[3];
  const float* mlp_w2 = (const float*)d_in[4];
  const float* mlp_b2 = (const float*)d_in[5];
  const float* fin_w = (const float*)d_in[6];
  const float* fin_b = (const float*)d_in[7];
  const float* lw[2][8];
  for (int l = 0; l < 2; ++l)
    for (int j = 0; j < 8; ++j) lw[l][j] = (const float*)d_in[8 + l * 8 + j];
  // lw[l]: 0 ah_w, 1 ah_b, 2 nr_w, 3 nr_b, 4 nh_w, 5 nh_b, 6 o_w, 7 o_b

  float* out = (float*)d_out;
  float* ws = (float*)d_ws;
  float* x0 = ws;                          // B*A*D floats
  float* x1 = x0 + (size_t)B_ * A_ * D_;
  float* nbr = x1 + (size_t)B_ * A_ * D_;  // B*ROWS*D
  float* scores = nbr + (size_t)B_ * ROWS_ * D_;  // B*A*40
  float* smax = scores + (size_t)B_ * A_ * 40;    // 640
  float* ssum = smax + 640;                       // 640

  const int agBlocks = (B_ * A_) / 16;  // 859
  mlp_kernel<<<agBlocks, 256, 0, stream>>>(agent, mlp_w1, mlp_b1, mlp_w2,
                                           mlp_b2, x0);

  float* xin = x0;
  float* xnext = x1;
  for (int l = 0; l < 2; ++l) {
    gemm_nbr_kernel<<<dim3(68, B_), 256, 0, stream>>>(adj, xin, nbr);
    heads_scores_kernel<<<agBlocks, 256, 0, stream>>>(
        xin, nbr, lw[l][0], lw[l][1], lw[l][2], lw[l][3], scores);
    softmax_reduce_kernel<<<B_ * 40, 256, 0, stream>>>(scores, smax, ssum);
    att_out_kernel<<<agBlocks, 256, 0, stream>>>(
        nbr, scores, smax, ssum, lw[l][4], lw[l][5], lw[l][6], lw[l][7],
        out + 128 + (size_t)l * A_ * 40, xnext);
    float* tmp = xin; xin = xnext; xnext = tmp;
  }
  // after the loop, xin holds the final x (in x0)
  qout_kernel<<<1, 128, 0, stream>>>(xin, fin_w, fin_b, out);
}